// Round 7
// baseline (236.044 us; speedup 1.0000x reference)
//
#include <hip/hip_runtime.h>
#include <math.h>

#define N_NODES 50000
#define N_EDGES 800000
#define CH 128
#define CAP 48   // slots per node; deg ~ Poisson(16), P(deg>=48) ~ 1e-10
#define SCAT_BLOCKS ((N_EDGES + 255) / 256)    // 3125
#define GEMM_BLOCKS ((N_NODES + 127) / 128)    // 391 (128 rows/block, 512 thr)
#define LOG2E 1.44269504088896f
#define LN2   0.69314718055995f

typedef __attribute__((ext_vector_type(8))) short short8;
typedef __attribute__((ext_vector_type(4))) float f32x4;
typedef __attribute__((ext_vector_type(2))) float f32x2;
union FragU { uint4 u; short8 s; };
struct GL { f32x4 a, b; };   // one edge's 8 channels (fp32, pre-scaled)

// RNE-pack two fp32 into (lo,hi) bf16 halves of a uint.
__device__ __forceinline__ unsigned pack_bf16(float a, float b) {
    unsigned ua = __float_as_uint(a);
    unsigned ub = __float_as_uint(b);
    ua += 0x7FFFu + ((ua >> 16) & 1u);
    ub += 0x7FFFu + ((ub >> 16) & 1u);
    return (ua >> 16) | (ub & 0xFFFF0000u);
}

// ---------------------------------------------------------------------------
// prep_pack: swizzle W_l,W_r (fp32 [out][in]) into MFMA B-fragment-ordered
// bf16 (layout proven round 7). Also zeroes counts (folds the memset dispatch).
__global__ __launch_bounds__(256) void prep_pack_kernel(
    const float* __restrict__ W_l, const float* __restrict__ W_r,
    uint4* __restrict__ Wf4, int* __restrict__ counts)
{
    int tid = blockIdx.x * 256 + threadIdx.x;   // grid 64 blocks -> 16384 threads
    if (tid < 2 * 8 * 4 * 64) {
        int lane  = tid & 63;
        int chunk = (tid >> 6) & 3;
        int tile  = (tid >> 8) & 7;
        int mat   = tid >> 11;
        const float* W = mat ? W_r : W_l;
        int n  = tile * 16 + (lane & 15);
        int k0 = chunk * 32 + (lane >> 4) * 8;
        const float* wp = W + n * CH + k0;
        float4 a = *(const float4*)wp;
        float4 b = *(const float4*)(wp + 4);
        uint4 p;
        p.x = pack_bf16(a.x, a.y);
        p.y = pack_bf16(a.z, a.w);
        p.z = pack_bf16(b.x, b.y);
        p.w = pack_bf16(b.z, b.w);
        Wf4[tid] = p;
    }
    for (int i = tid; i < N_NODES; i += 64 * 256) counts[i] = 0;
}

// ---------------------------------------------------------------------------
// Scatter (simplest proven form; rounds 0-4 showed all variants equal).
__global__ __launch_bounds__(256) void scatter_kernel(
    const int* __restrict__ src, const int* __restrict__ dst,
    const float* __restrict__ env,
    int* __restrict__ counts, unsigned* __restrict__ recs)
{
    int i = blockIdx.x * 256 + threadIdx.x;
    if (i < N_EDGES) {
        int d = dst[i];
        int rank = atomicAdd(&counts[d], 1);
        if (rank < CAP) {
            unsigned ev = __float_as_uint(env[i] + 1e-7f);
            ev += 0x7FFFu + ((ev >> 16) & 1u);     // RNE to bf16
            recs[d * CAP + rank] = (unsigned)src[i] | (ev & 0xFFFF0000u);
        }
    }
}

// ---------------------------------------------------------------------------
// MFMA GEMM: g_l = (q@W_l^T)*log2e, g_r = (q@W_r^T)*log2e — BOTH fp32.
// The log2e pre-scale lets node_attn use native v_exp_f32 (2^x) with no
// per-channel multiply; the inverse (ln2) folds into the final normalize.
// fp32 g_l also kills the 16-instr/group bf16 unpack in node_attn.
__global__ __launch_bounds__(512) void gemm_kernel(
    const float* __restrict__ q, const uint4* __restrict__ Wf4,
    float* __restrict__ g_lf, float* __restrict__ g_r)
{
    __shared__ uint4 sW[4096];   // 64 KB: both matrices, fragment-ordered
    for (int i = threadIdx.x; i < 4096; i += 512) sW[i] = Wf4[i];

    const int wv   = threadIdx.x >> 6;      // 0..7
    const int lane = threadIdx.x & 63;
    const int m    = lane & 15;
    const int quad = lane >> 4;
    const int row0 = blockIdx.x * 128 + wv * 16;

    int arow = row0 + m;
    if (arow >= N_NODES) arow = N_NODES - 1;   // clamp (stores guarded)
    const float* qr = q + (size_t)arow * CH + quad * 8;

    FragU A[4];
    #pragma unroll
    for (int c = 0; c < 4; ++c) {
        float4 x = *(const float4*)(qr + c * 32);
        float4 y = *(const float4*)(qr + c * 32 + 4);
        A[c].u.x = pack_bf16(x.x, x.y);
        A[c].u.y = pack_bf16(x.z, x.w);
        A[c].u.z = pack_bf16(y.x, y.y);
        A[c].u.w = pack_bf16(y.z, y.w);
    }

    __syncthreads();

    for (int mat = 0; mat < 2; ++mat) {
        float* gout = mat ? g_r : g_lf;
        for (int tile = 0; tile < 8; ++tile) {
            f32x4 acc = {0.f, 0.f, 0.f, 0.f};
            const uint4* bp = sW + (size_t)(mat * 8 + tile) * 256;
            #pragma unroll
            for (int c = 0; c < 4; ++c) {
                FragU B; B.u = bp[c * 64 + lane];
                acc = __builtin_amdgcn_mfma_f32_16x16x32_bf16(A[c].s, B.s, acc, 0, 0, 0);
            }
            int col = tile * 16 + m;
            #pragma unroll
            for (int r = 0; r < 4; ++r) {
                int rowg = row0 + quad * 4 + r;
                if (rowg < N_NODES)
                    gout[(size_t)rowg * CH + col] = acc[r] * LOG2E;
            }
        }
    }
}

// ---------------------------------------------------------------------------
// One wave per node, quarter-wave (16 lanes x 8 ch) per edge, 4 edges/group.
// V4 (round-6 post-mortem: VALU-ISSUE-bound at 85% busy -> cut instructions,
// not latency): single-group iter (pairing hurt), fp32 g_l (no unpack),
// log2e-folded exp2 (no pre-mul in expf), float2 packed math (v_pk_*_f32
// halves the non-trans VALU). Depth-3 gather prefetch as in R5.
__global__ __launch_bounds__(256) void node_attn_kernel(
    const f32x4* __restrict__ g_lf4, const float* __restrict__ g_r,
    const float* __restrict__ attn_w,
    const unsigned* __restrict__ recs, const int* __restrict__ counts,
    float* __restrict__ out)
{
    int gid = blockIdx.x * blockDim.x + threadIdx.x;
    int wid = gid >> 6;
    if (wid >= N_NODES) return;
    const int lane = threadIdx.x & 63;
    const int q4 = lane >> 4;    // quarter 0..3: which edge of the group of 4
    const int sl = lane & 15;    // sub-lane: channels sl*8 .. sl*8+7

    int cnt = counts[wid];
    if (cnt > CAP) cnt = CAP;

    f32x2 gr2[4], aw2[4];
    {
        const f32x4* grp = (const f32x4*)(g_r + (size_t)wid * CH + sl * 8);
        f32x4 a = grp[0], b = grp[1];
        gr2[0] = (f32x2){a.x, a.y}; gr2[1] = (f32x2){a.z, a.w};
        gr2[2] = (f32x2){b.x, b.y}; gr2[3] = (f32x2){b.z, b.w};
        const f32x4* awp = (const f32x4*)(attn_w + sl * 8);
        f32x4 c = awp[0], d = awp[1];
        aw2[0] = (f32x2){c.x, c.y}; aw2[1] = (f32x2){c.z, c.w};
        aw2[2] = (f32x2){d.x, d.y}; aw2[3] = (f32x2){d.z, d.w};
    }

    float l = 0.0f;
    f32x2 acc2[4] = {{0.f,0.f},{0.f,0.f},{0.f,0.f},{0.f,0.f}};

    if (cnt > 0) {
        const int clampi = cnt - 1;
        // whole bucket in one coalesced load (lanes >= cnt clamp to last slot)
        unsigned rcl = recs[wid * CAP + min(lane, clampi)];
        const int G = (cnt + 3) >> 2;   // groups of 4 edges

        #define REC_OF(jg, rv) { int e_ = (jg) * 4 + q4; if (e_ > clampi) e_ = clampi; \
                                 rv = __shfl(rcl, e_, 64); }
        #define GATHER(rv, gv) { const f32x4* p_ = g_lf4 + \
                                 (size_t)((rv) & 0xFFFFu) * (CH / 4) + sl * 2; \
                                 gv.a = p_[0]; gv.b = p_[1]; }

        unsigned r0, r1, r2, r3;
        GL g0, g1, g2, g3;
        REC_OF(0, r0); GATHER(r0, g0);
        r1 = r0; r2 = r0; g1 = g0; g2 = g0;
        if (G > 1) { REC_OF(1, r1); GATHER(r1, g1); }
        if (G > 2) { REC_OF(2, r2); GATHER(r2, g2); }

        for (int j = 0; j < G; ++j) {
            r3 = r0; g3 = g0;                 // init so tail rotation is defined
            if (j + 3 < G) {                  // wave-uniform branch
                REC_OF(j + 3, r3);
                GATHER(r3, g3);
            }

            bool active = (j * 4 + q4) < cnt;
            float ev = __uint_as_float(r0 & 0xFFFF0000u);

            f32x2 glv[4];
            glv[0] = (f32x2){g0.a.x, g0.a.y};
            glv[1] = (f32x2){g0.a.z, g0.a.w};
            glv[2] = (f32x2){g0.b.x, g0.b.y};
            glv[3] = (f32x2){g0.b.z, g0.b.w};

            f32x2 pv = {0.f, 0.f};
            #pragma unroll
            for (int c = 0; c < 4; ++c) {
                f32x2 h = glv[c] + gr2[c];                    // v_pk_add_f32
                f32x2 en;
                en.x = __builtin_amdgcn_exp2f(-h.x);          // native 2^x
                en.y = __builtin_amdgcn_exp2f(-h.y);
                f32x2 d1 = en + 1.0f;                         // v_pk_add_f32
                f32x2 sg;
                sg.x = __builtin_amdgcn_rcpf(d1.x);
                sg.y = __builtin_amdgcn_rcpf(d1.y);
                f32x2 t = h * aw2[c];                         // v_pk_mul_f32
                pv = __builtin_elementwise_fma(t, sg, pv);    // v_pk_fma_f32
            }
            float p = pv.x + pv.y;
            p += __shfl_xor(p, 1, 64);
            p += __shfl_xor(p, 2, 64);
            p += __shfl_xor(p, 4, 64);
            p += __shfl_xor(p, 8, 64);

            // p already includes the log2e factor (g pre-scaled) -> 2^p = e^p_true
            float w = __builtin_amdgcn_exp2f(p) * (active ? ev : 0.0f);
            l += w;
            f32x2 ws = {w, w};
            #pragma unroll
            for (int c = 0; c < 4; ++c)
                acc2[c] = __builtin_elementwise_fma(ws, glv[c], acc2[c]);

            r0 = r1; g0 = g1; r1 = r2; g1 = g2; r2 = r3; g2 = g3;
        }
        #undef REC_OF
        #undef GATHER
    }

    #pragma unroll
    for (int o = 16; o <= 32; o <<= 1) {
        l += __shfl_xor(l, o, 64);
        #pragma unroll
        for (int c = 0; c < 4; ++c) {
            acc2[c].x += __shfl_xor(acc2[c].x, o, 64);
            acc2[c].y += __shfl_xor(acc2[c].y, o, 64);
        }
    }

    if (q4 == 0) {
        // acc is scaled by log2e (g_l pre-scale); fold ln2 into the normalize.
        float inv = (l > 0.0f) ? __builtin_amdgcn_rcpf(l) * LN2 : 0.0f;
        float4 o0 = {acc2[0].x * inv, acc2[0].y * inv, acc2[1].x * inv, acc2[1].y * inv};
        float4 o1 = {acc2[2].x * inv, acc2[2].y * inv, acc2[3].x * inv, acc2[3].y * inv};
        float4* op = (float4*)(out + (size_t)wid * CH + sl * 8);
        op[0] = o0;
        op[1] = o1;
    }
}

// ---------------------------------------------------------------------------
extern "C" void kernel_launch(void* const* d_in, const int* in_sizes, int n_in,
                              void* d_out, int out_size, void* d_ws, size_t ws_size,
                              hipStream_t stream)
{
    const float* q      = (const float*)d_in[0];
    // d_in[1]=k, d_in[2]=v : unused (matches reference)
    const float* env    = (const float*)d_in[3];
    const float* W_l    = (const float*)d_in[4];
    const float* W_r    = (const float*)d_in[5];
    const float* attn_w = (const float*)d_in[6];
    const int*   eidx   = (const int*)d_in[7];
    const int* src = eidx;
    const int* dst = eidx + N_EDGES;
    float* out = (float*)d_out;

    float* ws    = (float*)d_ws;
    float* g_lf  = ws;                                   // N*CH fp32 (25.6 MB)
    float* g_r   = g_lf + (size_t)N_NODES * CH;          // N*CH fp32 (25.6 MB)
    uint4* Wf4   = (uint4*)(g_r + (size_t)N_NODES * CH); // 4096 uint4 = 64 KB
    unsigned* recs = (unsigned*)(Wf4 + 4096);            // N*CAP 4B records (9.6 MB)
    int* counts  = (int*)(recs + (size_t)N_NODES * CAP); // N

    prep_pack_kernel<<<64, 256, 0, stream>>>(W_l, W_r, Wf4, counts);

    scatter_kernel<<<SCAT_BLOCKS, 256, 0, stream>>>(src, dst, env, counts, recs);

    gemm_kernel<<<GEMM_BLOCKS, 512, 0, stream>>>(q, Wf4, g_lf, g_r);

    int node_wave_blocks = (N_NODES * 64 + 255) / 256;
    node_attn_kernel<<<node_wave_blocks, 256, 0, stream>>>(
        (const f32x4*)g_lf, g_r, attn_w, recs, counts, out);
}

// Round 8
// 225.861 us; speedup vs baseline: 1.0451x; 1.0451x over previous
//
#include <hip/hip_runtime.h>
#include <math.h>

#define N_NODES 50000
#define N_EDGES 800000
#define CH 128
#define CAP 48   // slots per node; deg ~ Poisson(16), P(deg>=48) ~ 1e-10
#define SCAT_BLOCKS ((N_EDGES + 255) / 256)    // 3125
#define GEMM_BLOCKS ((N_NODES + 127) / 128)    // 391 (128 rows/block, 512 thr)
#define LOG2E 1.44269504088896f
#define LN2   0.69314718055995f

typedef __attribute__((ext_vector_type(8))) short short8;
typedef __attribute__((ext_vector_type(4))) float f32x4;
typedef __attribute__((ext_vector_type(2))) float f32x2;
union FragU { uint4 u; short8 s; };

// RNE-pack two fp32 into (lo,hi) bf16 halves of a uint.
__device__ __forceinline__ unsigned pack_bf16(float a, float b) {
    unsigned ua = __float_as_uint(a);
    unsigned ub = __float_as_uint(b);
    ua += 0x7FFFu + ((ua >> 16) & 1u);
    ub += 0x7FFFu + ((ub >> 16) & 1u);
    return (ua >> 16) | (ub & 0xFFFF0000u);
}

// ---------------------------------------------------------------------------
// prep_pack: swizzle W_l,W_r (fp32 [out][in]) into MFMA B-fragment-ordered
// bf16 (layout proven round 7). Also zeroes counts (folds the memset dispatch).
__global__ __launch_bounds__(256) void prep_pack_kernel(
    const float* __restrict__ W_l, const float* __restrict__ W_r,
    uint4* __restrict__ Wf4, int* __restrict__ counts)
{
    int tid = blockIdx.x * 256 + threadIdx.x;   // grid 64 blocks -> 16384 threads
    if (tid < 2 * 8 * 4 * 64) {
        int lane  = tid & 63;
        int chunk = (tid >> 6) & 3;
        int tile  = (tid >> 8) & 7;
        int mat   = tid >> 11;
        const float* W = mat ? W_r : W_l;
        int n  = tile * 16 + (lane & 15);
        int k0 = chunk * 32 + (lane >> 4) * 8;
        const float* wp = W + n * CH + k0;
        float4 a = *(const float4*)wp;
        float4 b = *(const float4*)(wp + 4);
        uint4 p;
        p.x = pack_bf16(a.x, a.y);
        p.y = pack_bf16(a.z, a.w);
        p.z = pack_bf16(b.x, b.y);
        p.w = pack_bf16(b.z, b.w);
        Wf4[tid] = p;
    }
    for (int i = tid; i < N_NODES; i += 64 * 256) counts[i] = 0;
}

// ---------------------------------------------------------------------------
// Scatter (simplest proven form; rounds 0-4 showed all variants equal).
__global__ __launch_bounds__(256) void scatter_kernel(
    const int* __restrict__ src, const int* __restrict__ dst,
    const float* __restrict__ env,
    int* __restrict__ counts, unsigned* __restrict__ recs)
{
    int i = blockIdx.x * 256 + threadIdx.x;
    if (i < N_EDGES) {
        int d = dst[i];
        int rank = atomicAdd(&counts[d], 1);
        if (rank < CAP) {
            unsigned ev = __float_as_uint(env[i] + 1e-7f);
            ev += 0x7FFFu + ((ev >> 16) & 1u);     // RNE to bf16
            recs[d * CAP + rank] = (unsigned)src[i] | (ev & 0xFFFF0000u);
        }
    }
}

// ---------------------------------------------------------------------------
// MFMA GEMM: g_l = bf16((q@W_l^T)*log2e), g_r = fp32((q@W_r^T)*log2e).
// Round-8: bf16 g_l restored (round-7's fp32 g_l DOUBLED gather FETCH 94.5
// -> 190 MB and tipped node_attn gather-bound); the log2e pre-scale is kept
// (native exp2 in node_attn, ln2 un-scale folded into the normalize).
__global__ __launch_bounds__(512) void gemm_kernel(
    const float* __restrict__ q, const uint4* __restrict__ Wf4,
    unsigned short* __restrict__ g_l16, float* __restrict__ g_r)
{
    __shared__ uint4 sW[4096];   // 64 KB: both matrices, fragment-ordered
    for (int i = threadIdx.x; i < 4096; i += 512) sW[i] = Wf4[i];

    const int wv   = threadIdx.x >> 6;      // 0..7
    const int lane = threadIdx.x & 63;
    const int m    = lane & 15;
    const int quad = lane >> 4;
    const int row0 = blockIdx.x * 128 + wv * 16;

    int arow = row0 + m;
    if (arow >= N_NODES) arow = N_NODES - 1;   // clamp (stores guarded)
    const float* qr = q + (size_t)arow * CH + quad * 8;

    FragU A[4];
    #pragma unroll
    for (int c = 0; c < 4; ++c) {
        float4 x = *(const float4*)(qr + c * 32);
        float4 y = *(const float4*)(qr + c * 32 + 4);
        A[c].u.x = pack_bf16(x.x, x.y);
        A[c].u.y = pack_bf16(x.z, x.w);
        A[c].u.z = pack_bf16(y.x, y.y);
        A[c].u.w = pack_bf16(y.z, y.w);
    }

    __syncthreads();

    for (int mat = 0; mat < 2; ++mat) {
        for (int tile = 0; tile < 8; ++tile) {
            f32x4 acc = {0.f, 0.f, 0.f, 0.f};
            const uint4* bp = sW + (size_t)(mat * 8 + tile) * 256;
            #pragma unroll
            for (int c = 0; c < 4; ++c) {
                FragU B; B.u = bp[c * 64 + lane];
                acc = __builtin_amdgcn_mfma_f32_16x16x32_bf16(A[c].s, B.s, acc, 0, 0, 0);
            }
            int col = tile * 16 + m;
            #pragma unroll
            for (int r = 0; r < 4; ++r) {
                int rowg = row0 + quad * 4 + r;
                if (rowg < N_NODES) {
                    float v = acc[r] * LOG2E;
                    if (mat == 0) {
                        unsigned u = __float_as_uint(v);
                        u += 0x7FFFu + ((u >> 16) & 1u);
                        g_l16[(size_t)rowg * CH + col] = (unsigned short)(u >> 16);
                    } else {
                        g_r[(size_t)rowg * CH + col] = v;
                    }
                }
            }
        }
    }
}

// ---------------------------------------------------------------------------
// One wave per node, quarter-wave (16 lanes x 8 ch) per edge, 4 edges/group.
// V5 = R5 memory behavior (bf16 gathers: 256B/edge, FETCH ~95MB) + R7 VALU
// cuts (exp2 with log2e pre-baked into g -> no pre-mul; v_pk_*_f32 packed
// math). Depth-3 gather prefetch; whole bucket preloaded coalesced.
__global__ __launch_bounds__(256) void node_attn_kernel(
    const uint4* __restrict__ g_lb4, const float* __restrict__ g_r,
    const float* __restrict__ attn_w,
    const unsigned* __restrict__ recs, const int* __restrict__ counts,
    float* __restrict__ out)
{
    int gid = blockIdx.x * blockDim.x + threadIdx.x;
    int wid = gid >> 6;
    if (wid >= N_NODES) return;
    const int lane = threadIdx.x & 63;
    const int q4 = lane >> 4;    // quarter 0..3: which edge of the group of 4
    const int sl = lane & 15;    // sub-lane: channels sl*8 .. sl*8+7

    int cnt = counts[wid];
    if (cnt > CAP) cnt = CAP;

    f32x2 gr2[4], aw2[4];
    {
        const f32x4* grp = (const f32x4*)(g_r + (size_t)wid * CH + sl * 8);
        f32x4 a = grp[0], b = grp[1];
        gr2[0] = (f32x2){a.x, a.y}; gr2[1] = (f32x2){a.z, a.w};
        gr2[2] = (f32x2){b.x, b.y}; gr2[3] = (f32x2){b.z, b.w};
        const f32x4* awp = (const f32x4*)(attn_w + sl * 8);
        f32x4 c = awp[0], d = awp[1];
        aw2[0] = (f32x2){c.x, c.y}; aw2[1] = (f32x2){c.z, c.w};
        aw2[2] = (f32x2){d.x, d.y}; aw2[3] = (f32x2){d.z, d.w};
    }

    float l = 0.0f;
    f32x2 acc2[4] = {{0.f,0.f},{0.f,0.f},{0.f,0.f},{0.f,0.f}};

    if (cnt > 0) {
        const int clampi = cnt - 1;
        // whole bucket in one coalesced load (lanes >= cnt clamp to last slot)
        unsigned rcl = recs[wid * CAP + min(lane, clampi)];
        const int G = (cnt + 3) >> 2;   // groups of 4 edges

        #define REC_OF(jg, rv) { int e_ = (jg) * 4 + q4; if (e_ > clampi) e_ = clampi; \
                                 rv = __shfl(rcl, e_, 64); }
        #define GATHER(rv) g_lb4[(size_t)((rv) & 0xFFFFu) * (CH / 8) + sl]

        unsigned r0, r1, r2, r3;
        uint4 g0, g1, g2, g3;
        REC_OF(0, r0); g0 = GATHER(r0);
        r1 = r0; r2 = r0; g1 = g0; g2 = g0;
        if (G > 1) { REC_OF(1, r1); g1 = GATHER(r1); }
        if (G > 2) { REC_OF(2, r2); g2 = GATHER(r2); }

        for (int j = 0; j < G; ++j) {
            r3 = r0; g3 = g0;                 // init so tail rotation is defined
            if (j + 3 < G) {                  // wave-uniform branch
                REC_OF(j + 3, r3);
                g3 = GATHER(r3);
            }

            bool active = (j * 4 + q4) < cnt;
            float ev = __uint_as_float(r0 & 0xFFFF0000u);

            // unpack 8 bf16 channels (already log2e-scaled) into 4 f32x2
            f32x2 glv[4];
            glv[0] = (f32x2){__uint_as_float(g0.x << 16),
                             __uint_as_float(g0.x & 0xFFFF0000u)};
            glv[1] = (f32x2){__uint_as_float(g0.y << 16),
                             __uint_as_float(g0.y & 0xFFFF0000u)};
            glv[2] = (f32x2){__uint_as_float(g0.z << 16),
                             __uint_as_float(g0.z & 0xFFFF0000u)};
            glv[3] = (f32x2){__uint_as_float(g0.w << 16),
                             __uint_as_float(g0.w & 0xFFFF0000u)};

            f32x2 pv = {0.f, 0.f};
            #pragma unroll
            for (int c = 0; c < 4; ++c) {
                f32x2 h = glv[c] + gr2[c];                    // v_pk_add_f32
                f32x2 en;
                en.x = __builtin_amdgcn_exp2f(-h.x);          // native 2^x
                en.y = __builtin_amdgcn_exp2f(-h.y);
                f32x2 d1 = en + 1.0f;                         // v_pk_add_f32
                f32x2 sg;
                sg.x = __builtin_amdgcn_rcpf(d1.x);
                sg.y = __builtin_amdgcn_rcpf(d1.y);
                f32x2 t = h * aw2[c];                         // v_pk_mul_f32
                pv = __builtin_elementwise_fma(t, sg, pv);    // v_pk_fma_f32
            }
            float p = pv.x + pv.y;
            p += __shfl_xor(p, 1, 64);
            p += __shfl_xor(p, 2, 64);
            p += __shfl_xor(p, 4, 64);
            p += __shfl_xor(p, 8, 64);

            // p carries the log2e factor (g pre-scaled) -> 2^p = e^p_true
            float w = __builtin_amdgcn_exp2f(p) * (active ? ev : 0.0f);
            l += w;
            f32x2 ws = {w, w};
            #pragma unroll
            for (int c = 0; c < 4; ++c)
                acc2[c] = __builtin_elementwise_fma(ws, glv[c], acc2[c]);

            r0 = r1; g0 = g1; r1 = r2; g1 = g2; r2 = r3; g2 = g3;
        }
        #undef REC_OF
        #undef GATHER
    }

    #pragma unroll
    for (int o = 16; o <= 32; o <<= 1) {
        l += __shfl_xor(l, o, 64);
        #pragma unroll
        for (int c = 0; c < 4; ++c) {
            acc2[c].x += __shfl_xor(acc2[c].x, o, 64);
            acc2[c].y += __shfl_xor(acc2[c].y, o, 64);
        }
    }

    if (q4 == 0) {
        // acc is scaled by log2e (g_l pre-scale); fold ln2 into the normalize.
        float inv = (l > 0.0f) ? __builtin_amdgcn_rcpf(l) * LN2 : 0.0f;
        float4 o0 = {acc2[0].x * inv, acc2[0].y * inv, acc2[1].x * inv, acc2[1].y * inv};
        float4 o1 = {acc2[2].x * inv, acc2[2].y * inv, acc2[3].x * inv, acc2[3].y * inv};
        float4* op = (float4*)(out + (size_t)wid * CH + sl * 8);
        op[0] = o0;
        op[1] = o1;
    }
}

// ---------------------------------------------------------------------------
extern "C" void kernel_launch(void* const* d_in, const int* in_sizes, int n_in,
                              void* d_out, int out_size, void* d_ws, size_t ws_size,
                              hipStream_t stream)
{
    const float* q      = (const float*)d_in[0];
    // d_in[1]=k, d_in[2]=v : unused (matches reference)
    const float* env    = (const float*)d_in[3];
    const float* W_l    = (const float*)d_in[4];
    const float* W_r    = (const float*)d_in[5];
    const float* attn_w = (const float*)d_in[6];
    const int*   eidx   = (const int*)d_in[7];
    const int* src = eidx;
    const int* dst = eidx + N_EDGES;
    float* out = (float*)d_out;

    float* ws    = (float*)d_ws;
    unsigned* g_lb = (unsigned*)ws;                      // N*CH/2 uints (bf16 pairs)
    float* g_r   = (float*)(g_lb + (size_t)N_NODES * (CH / 2));  // N*CH fp32
    uint4* Wf4   = (uint4*)(g_r + (size_t)N_NODES * CH); // 4096 uint4 = 64 KB
    unsigned* recs = (unsigned*)(Wf4 + 4096);            // N*CAP 4B records (9.6 MB)
    int* counts  = (int*)(recs + (size_t)N_NODES * CAP); // N

    prep_pack_kernel<<<64, 256, 0, stream>>>(W_l, W_r, Wf4, counts);

    scatter_kernel<<<SCAT_BLOCKS, 256, 0, stream>>>(src, dst, env, counts, recs);

    gemm_kernel<<<GEMM_BLOCKS, 512, 0, stream>>>(
        q, Wf4, (unsigned short*)g_lb, g_r);

    int node_wave_blocks = (N_NODES * 64 + 255) / 256;
    node_attn_kernel<<<node_wave_blocks, 256, 0, stream>>>(
        (const uint4*)g_lb, g_r, attn_w, recs, counts, out);
}